// Round 5
// baseline (6443.198 us; speedup 1.0000x reference)
//
#include <hip/hip_runtime.h>
#include <cstdint>
#include <cstddef>

// Problem constants
#define BB   64     // batch
#define TT   512    // time steps
#define HH   256    // hidden
#define G4   1024   // 4*H
#define NL   8      // layers
#define NW   32     // workgroups per layer (hidden-unit slices)
#define HPW  8      // hidden units per WG
#define NR   32     // gate rows per WG (4 gates * HPW)
#define NS   16     // independent batch streams per layer
#define BR   4      // batch rows per stream (NS*BR = BB)

// Watchdog: poll breaks after this many iterations and proceeds (bounded
// wrong-answer instead of GPU hang). Never triggers when protocol is sound.
#define POLL_BOUND (1 << 17)

typedef _Float16 half8 __attribute__((ext_vector_type(8)));
typedef float   floatx4 __attribute__((ext_vector_type(4)));

__device__ __forceinline__ float sigm(float v)   { return 1.0f / (1.0f + __expf(-v)); }
__device__ __forceinline__ float tanh_f(float v) { return 1.0f - 2.0f / (__expf(2.0f * v) + 1.0f); }

// ---- coherence helpers (ONLY the proven system-scope primitives) ----------
// sc0 sc1: bypass L1+L2, coherence point = memory-side IF$. Proven protocol:
//   producer: data stores sc0sc1 -> s_waitcnt vmcnt(0) -> flag store sc0sc1
//   consumer: poll flag sc0sc1; then PLAIN cached loads of data (safe because
//   every data address is written exactly once per launch and only read after
//   the flag: first-touch L2 fill pulls post-store bytes from IF$).
// The R1-R4 sc0-only "L2-scope" experiments are abandoned: two independent
// implementations failed with identical small errors -> sc0 alone provides no
// reliable cross-CU release/acquire (scope bits: sc0 sc1 = system; sc0 ~ WG).
__device__ __forceinline__ void gstore8_x(_Float16* p, half8 d) {
  asm volatile("global_store_dwordx4 %0, %1, off sc0 sc1" :: "v"(p), "v"(d) : "memory");
}
__device__ __forceinline__ void stdword_x(int* p, int v) {
  asm volatile("global_store_dword %0, %1, off sc0 sc1" :: "v"(p), "v"(v) : "memory");
}
__device__ __forceinline__ void wait_vm0() {
  asm volatile("s_waitcnt vmcnt(0)" ::: "memory");
}
__device__ __forceinline__ int ldflag_x(const int* p) {
  int v; asm volatile("global_load_dword %0, %1, off sc0 sc1" : "=v"(v) : "v"(p) : "memory");
  wait_vm0(); return v;
}
__device__ __forceinline__ void ldflag2_x(const int* p1, const int* p2, int& v1, int& v2) {
  asm volatile("global_load_dword %0, %2, off sc0 sc1\n\t"
               "global_load_dword %1, %3, off sc0 sc1\n\t"
               "s_waitcnt vmcnt(0)"
               : "=&v"(v1), "=&v"(v2) : "v"(p1), "v"(p2) : "memory");
}

// hseq layout per layer per t: [s(16)][kblk(32)][row(4)][8] fp16
//   (stream-blocked MFMA A-fragment layout; kblk = hidden/8)
#define TSTRIDE ((size_t)NS * 32 * BR * 8)    // 16384 elems per t (32KB)
#define LSTRIDE ((size_t)TT * TSTRIDE)        // 8,388,608 elems per layer (16MB)

// ---------------------------------------------------------------------------
// xg0 table: table[v][n] = sum_e emb[v][e] * Wih0[n][e]   (biases NOT included)
__global__ void build_xg0(const float* __restrict__ emb, const float* __restrict__ Wih0,
                          float* __restrict__ table) {
  int i = blockIdx.x * 256 + threadIdx.x;
  if (i >= 23 * G4) return;
  int v = i >> 10, n = i & (G4 - 1);
  float a = 0.f;
#pragma unroll
  for (int e = 0; e < 16; ++e) a += emb[v * 16 + e] * Wih0[n * 16 + e];
  table[i] = a;
}

// ---------------------------------------------------------------------------
// Persistent stream-decoupled LSTM.
// grid = 256 WGs (NL layers x NW hidden-slices) x 1024 threads = 16 waves.
// Wave wv of WG (l,w) owns stream s=wv: batch rows 4s..4s+3, hidden rows
// 8w..8w+7 (all 4 gates). Each wave runs its own chain with NO intra-WG
// barriers in the main loop:
//   poll flag[l][s][0..31] >= t (recurrent) and flag[l-1][s][0..31] >= t+1
//   (forward) -> plain-load A-fragments -> 16+16 MFMAs (M=4 padded in 16)
//   -> C transpose via per-wave LDS scratch (wave-local, lgkmcnt only)
//   -> cell update (32 lanes: 4 rows x 8 hidden) -> publish 4x16B sc0sc1
//   -> vmcnt(0) -> flag[l][s][w] = t+1.
// 16 independent chains per layer advance concurrently; wall-clock ~ per-step
// IF$ chain latency instead of the old barrier-coupled lock-step.
__global__ __launch_bounds__(1024, 4) void lstm_pipeline(
    const int*   __restrict__ x,         // [B][T]
    const float* __restrict__ Wih_rest,  // [7][1024][256]
    const float* __restrict__ Whh,       // [8][1024][256]
    const float* __restrict__ bih,       // [8][1024]
    const float* __restrict__ bhh,       // [8][1024]
    const float* __restrict__ xg0t,      // [23][1024]
    _Float16* __restrict__ hseq,         // NL * LSTRIDE fp16
    int* __restrict__ flag)              // [NL][NS][NW] step counters (IF$)
{
  const int l   = blockIdx.x & 7;
  const int w   = blockIdx.x >> 3;
  const int tid = threadIdx.x;
  const int lane = tid & 63;
  const int wv   = tid >> 6;        // wave index = stream s (0..15)

  __shared__ __align__(16) _Float16 wlds[64 * NR * 8]; // [kc 0..63][n 0..31][8] 32KB
  __shared__ float  blds[NR];
  __shared__ float  tlds[23 * NR];
  __shared__ float  csc[NS][BR][33];                   // per-wave C scratch (padded)
  __shared__ __align__(16) _Float16 hsc[NS][BR][8];    // per-wave h staging

  // ---- one-time init: gather this WG's 32 gate rows into LDS as fp16 ----
  for (int idx = tid; idx < 64 * NR; idx += 1024) {
    int kc = idx >> 5;          // 0..31 input half, 32..63 recurrent half
    int n  = idx & 31;
    int g = n >> 3, jl = n & 7;
    int gr = g * 256 + w * HPW + jl;
    float v[8];
    if (kc < 32) {
      if (l == 0) { for (int j = 0; j < 8; ++j) v[j] = 0.f; }
      else {
        const float* src = Wih_rest + ((size_t)(l - 1) * G4 + gr) * HH + kc * 8;
        for (int j = 0; j < 8; ++j) v[j] = src[j];
      }
    } else {
      const float* src = Whh + ((size_t)l * G4 + gr) * HH + (kc - 32) * 8;
      for (int j = 0; j < 8; ++j) v[j] = src[j];
    }
    _Float16* dst = wlds + (size_t)idx * 8;
    for (int j = 0; j < 8; ++j) dst[j] = (_Float16)v[j];
  }
  if (tid < NR) {
    int g = tid >> 3, jl = tid & 7;
    int gr = g * 256 + w * HPW + jl;
    blds[tid] = bih[l * G4 + gr] + bhh[l * G4 + gr];
  }
  if (l == 0 && tid < 23 * NR) {
    int v = tid >> 5, n = tid & 31;
    int g = n >> 3, jl = n & 7;
    tlds[tid] = xg0t[v * G4 + g * 256 + w * HPW + jl];
  }
  // agent-scope acquire: invalidate any stale L1/L2 lines before cached reads
  if (tid == 0) (void)__hip_atomic_load(flag, __ATOMIC_ACQUIRE, __HIP_MEMORY_SCOPE_AGENT);
  __syncthreads();   // the ONLY barrier; main loop below is barrier-free

  // ---- per-wave constants ----
  const int s    = wv;
  const int kq   = lane >> 4;            // k-chunk quarter within 32-wide tile
  const int c0   = lane & 15;            // MFMA col (tile0) == wlds row c0
  const int aoff = (lane & 3) * 8;       // A-frag: row m holds batch (m&3)
  const int cb   = lane & 3;             // cell: batch row within stream
  const int cj   = (lane >> 2) & 7;      // cell: hidden unit within slice

  float bi0 = 0.f, bi1 = 0.f, bi2 = 0.f, bi3 = 0.f;
  if (lane < 32) {
    bi0 = blds[cj]; bi1 = blds[8 + cj]; bi2 = blds[16 + cj]; bi3 = blds[24 + cj];
  }

  const _Float16* hin  = hseq + (size_t)(l > 0 ? l - 1 : 0) * LSTRIDE + s * (32 * BR * 8);
  _Float16*       hrec = hseq + (size_t)l * LSTRIDE + s * (32 * BR * 8);
  int*       fown = flag + (l * NS + s) * NW;
  const int* f1p  = fown + (lane & 31);                                  // recurrent
  const int* f2p  = flag + ((l > 0 ? l - 1 : 0) * NS + s) * NW + (lane & 31); // forward

  float cst = 0.f;   // c-state for (cb, cj), lanes < 32

  for (int t = 0; t < TT; ++t) {
    // ---- poll (this wave only; no cross-wave coupling) ----
    if (t > 0 || l > 0) {
      for (int it = 0; it < POLL_BOUND; ++it) {
        bool ok;
        if (t > 0 && l > 0) {
          int v1, v2; ldflag2_x(f1p, f2p, v1, v2);
          ok = (v1 >= t) && (v2 >= t + 1);
        } else if (t > 0) {
          ok = (ldflag_x(f1p) >= t);
        } else {
          ok = (ldflag_x(f2p) >= 1);
        }
        if (__all(ok)) break;
        __builtin_amdgcn_s_sleep(1);
      }
    }

    // ---- MFMA phase: gates[4 rows x 32 gate-cols] for this stream ----
    floatx4 acc0 = {0.f, 0.f, 0.f, 0.f};
    floatx4 acc1 = {0.f, 0.f, 0.f, 0.f};
    if (l > 0) {
      const _Float16* ain = hin + (size_t)t * TSTRIDE;
      half8 a[8];
#pragma unroll
      for (int kt = 0; kt < 8; ++kt)
        a[kt] = *(const half8*)(ain + (((kt * 4 + kq) * BR * 8) + aoff));
#pragma unroll
      for (int kt = 0; kt < 8; ++kt) {
        int kc = kt * 4 + kq;
        half8 w0 = *(const half8*)(wlds + ((kc * 32 + c0) << 3));
        half8 w1 = *(const half8*)(wlds + ((kc * 32 + 16 + c0) << 3));
        acc0 = __builtin_amdgcn_mfma_f32_16x16x32_f16(a[kt], w0, acc0, 0, 0, 0);
        acc1 = __builtin_amdgcn_mfma_f32_16x16x32_f16(a[kt], w1, acc1, 0, 0, 0);
      }
    }
    if (t > 0) {
      const _Float16* rin = hrec + (size_t)(t - 1) * TSTRIDE;
      half8 a[8];
#pragma unroll
      for (int kt = 0; kt < 8; ++kt)
        a[kt] = *(const half8*)(rin + (((kt * 4 + kq) * BR * 8) + aoff));
#pragma unroll
      for (int kt = 0; kt < 8; ++kt) {
        int kc = kt * 4 + kq;
        half8 w0 = *(const half8*)(wlds + (((32 + kc) * 32 + c0) << 3));
        half8 w1 = *(const half8*)(wlds + (((32 + kc) * 32 + 16 + c0) << 3));
        acc0 = __builtin_amdgcn_mfma_f32_16x16x32_f16(a[kt], w0, acc0, 0, 0, 0);
        acc1 = __builtin_amdgcn_mfma_f32_16x16x32_f16(a[kt], w1, acc1, 0, 0, 0);
      }
    }

    // ---- C -> per-wave LDS scratch (rows 0..3 valid; 4..15 are dups) ----
    if ((lane >> 4) == 0) {
#pragma unroll
      for (int r = 0; r < 4; ++r) {
        csc[wv][r][c0]      = acc0[r];
        csc[wv][r][16 + c0] = acc1[r];
      }
    }
    // wave-local LDS ordering: in-order LDS pipe + data-return wait; the
    // memory clobber stops compiler reordering reads above the writes.
    asm volatile("s_waitcnt lgkmcnt(0)" ::: "memory");

    // ---- cell update: lanes 0..31 handle (batch cb, hidden cj) ----
    if (lane < 32) {
      float gi = csc[wv][cb][cj]      + bi0;
      float gf = csc[wv][cb][8 + cj]  + bi1;
      float gg = csc[wv][cb][16 + cj] + bi2;
      float go = csc[wv][cb][24 + cj] + bi3;
      if (l == 0) {
        int xv = x[(s * BR + cb) * TT + t];
        const float* tb = tlds + xv * NR;
        gi += tb[cj]; gf += tb[8 + cj]; gg += tb[16 + cj]; go += tb[24 + cj];
      }
      float iv = sigm(gi), fv = sigm(gf), gv = tanh_f(gg), ov = sigm(go);
      cst = fv * cst + iv * gv;
      float hv = ov * tanh_f(cst);
      hsc[wv][cb][cj] = (_Float16)hv;
    }
    asm volatile("s_waitcnt lgkmcnt(0)" ::: "memory");

    // ---- publish: 4 lanes x 16B sc0sc1, vmcnt(0), flag release ----
    if (lane < 4) {
      half8 hv8 = *(const half8*)&hsc[wv][lane][0];
      gstore8_x(hrec + (size_t)t * TSTRIDE + (w * BR + lane) * 8, hv8);
    }
    wait_vm0();
    if (lane == 0) stdword_x(fown + w, t + 1);
  }
}

// ---------------------------------------------------------------------------
// Final projection: out[b][t][v] = h7[b][t][:] . fc_w[v][:] + fc_b[v]
__global__ __launch_bounds__(256) void fc_kernel(
    const _Float16* __restrict__ hseq7,  // [T][s16][kblk32][row4][8] fp16
    const float* __restrict__ fcw,       // [23][256]
    const float* __restrict__ fcb,       // [23]
    float* __restrict__ out)             // [64][512][23]
{
  const int t = blockIdx.x;
  const int tid = threadIdx.x;
  __shared__ __align__(16) _Float16 hbuf[NS * 32 * BR * 8];
  __shared__ float wbuf[23 * 256];
  __shared__ float bbuf[24];

  const _Float16* src = hseq7 + (size_t)t * TSTRIDE;
  for (int i = tid; i < NS * 32 * BR; i += 256)
    ((half8*)hbuf)[i] = ((const half8*)src)[i];
  for (int i = tid; i < 23 * 256; i += 256) wbuf[i] = fcw[i];
  if (tid < 23) bbuf[tid] = fcb[tid];
  __syncthreads();

  for (int o = tid; o < 64 * 23; o += 256) {
    int b = o / 23, v = o - b * 23;
    int s = b >> 2, r = b & 3;
    float acc = bbuf[v];
#pragma unroll 4
    for (int kc = 0; kc < 32; ++kc) {
      half8 hv = *(const half8*)(hbuf + (size_t)s * (32 * BR * 8) + (kc * BR + r) * 8);
      const float* wr = wbuf + v * 256 + kc * 8;
#pragma unroll
      for (int j = 0; j < 8; ++j) acc += (float)hv[j] * wr[j];
    }
    out[((size_t)b * TT + t) * 23 + v] = acc;
  }
}

// ---------------------------------------------------------------------------
extern "C" void kernel_launch(void* const* d_in, const int* in_sizes, int n_in,
                              void* d_out, int out_size, void* d_ws, size_t ws_size,
                              hipStream_t stream) {
  const int*   x        = (const int*)d_in[0];
  const float* emb      = (const float*)d_in[1];
  const float* Wih0     = (const float*)d_in[2];
  const float* Wih_rest = (const float*)d_in[3];
  const float* Whh      = (const float*)d_in[4];
  const float* bihp     = (const float*)d_in[5];
  const float* bhhp     = (const float*)d_in[6];
  const float* fcw      = (const float*)d_in[7];
  const float* fcb      = (const float*)d_in[8];
  float* out = (float*)d_out;

  char* ws = (char*)d_ws;
  // ws layout:
  // flag @0: NL*NS*NW*4 = 16KB | table @16384 | hseq @131072 (128MB)
  int*      flag  = (int*)ws;
  float*    table = (float*)(ws + 16384);              // 23*1024*4 = 94208 B
  _Float16* hseq  = (_Float16*)(ws + 131072);          // 8 * 16 MB

  hipMemsetAsync(ws, 0, 16384, stream);  // step-counter flags
  build_xg0<<<(23 * G4 + 255) / 256, 256, 0, stream>>>(emb, Wih0, table);
  lstm_pipeline<<<NL * NW, 1024, 0, stream>>>(x, Wih_rest, Whh, bihp, bhhp, table, hseq, flag);
  fc_kernel<<<TT, 256, 0, stream>>>(hseq + (size_t)7 * LSTRIDE, fcw, fcb, out);
}